// Round 6
// baseline (94.200 us; speedup 1.0000x reference)
//
#include <hip/hip_runtime.h>

typedef float v2f __attribute__((ext_vector_type(2)));

constexpr int S = 512, B = 8192, H = 5;
constexpr float KN1 = -1.44269504088896340736f;   // -log2(e)
constexpr float KN2 = 2.0f * KN1;                 // -2*log2(e)

__device__ __forceinline__ float fexp2(float x) { return __builtin_amdgcn_exp2f(x); }
__device__ __forceinline__ float frcp(float x)  { return __builtin_amdgcn_rcpf(x); }

// ds_swizzle BitMode (epilogue reduction only): imm = xor<<10 | or<<5 | and
#define SWZ(v, imm) __int_as_float(__builtin_amdgcn_ds_swizzle(__float_as_int(v), (imm)))
// DPP row_ror:N within 16-lane rows: lane l RECEIVES lane (l-N)&15 (rotate
// right = data moves toward higher lanes; same convention as row_shr scans).
// For N=8 this coincides with (l+8)&15, which is why R3/R4 never caught it.
#define ROR8(v) __int_as_float(__builtin_amdgcn_mov_dpp(__float_as_int(v), 0x128, 0xF, 0xF, false))
#define ROR1(v) __int_as_float(__builtin_amdgcn_mov_dpp(__float_as_int(v), 0x121, 0xF, 0xF, false))

// 16 lanes per chain: lane = u*8+j; u0 owns rows {i,g}, u1 owns {f,o};
// CS,h valid on u1. h distributed via VALU-pipe DPP rotation (no LDS pipe
// in the recurrence): hsel(l) = h_{l&7}; after m ROR1s lane j holds
// h_{(j-m)&7}, so rotation weights are indexed k=(j-m)&7 (zeros for k>=H).
// Algebra: weights pre-scaled by -log2e / -2log2e; cell state kept SCALED
// (CS = c*KN2) so tanh needs just exp2(CS); g-row epilogue folds KN2
// (gK = g*KN2 on u0, = o on u1); h = fma(rt, 2o, -o).
// 8192 chains * 16 = 131072 threads = 2048 waves = 2 waves/SIMD.
__global__ __launch_bounds__(256, 2) void lstm_kernel(
    const float* __restrict__ x,      // [S,B,2]
    const float* __restrict__ W_ih,   // [4H,2]
    const float* __restrict__ W_hh,   // [4H,H]
    const float* __restrict__ b_ih,   // [4H]
    const float* __restrict__ b_hh,   // [4H]
    const float* __restrict__ W_lin,  // [1,H]
    const float* __restrict__ b_lin,  // [1]
    float* __restrict__ out)          // [B,1]
{
  const int tid   = blockIdx.x * blockDim.x + threadIdx.x;
  const int chain = tid >> 4;
  const int l     = tid & 15;
  const int u     = l >> 3;
  const int j     = l & 7;
  const int jm    = (j < H) ? j : H - 1;

  const int r1 = (u ? H : 0) + jm;           // act1: i(u0) / f(u1)
  const int r2 = (u ? 3 * H : 2 * H) + jm;   // act2: g(u0) / o(u1)
  const float s2 = u ? KN1 : KN2;            // g rows scaled by -2log2e
  const float eA = u ? 1.0f : 2.0f * KN2;    // gK = r*eA + eB
  const float eB = u ? 0.0f : -KN2;          //   u0: g*KN2 ; u1: o

  v2f wx0 = {W_ih[r1 * 2 + 0] * KN1, W_ih[r2 * 2 + 0] * s2};
  v2f wx1 = {W_ih[r1 * 2 + 1] * KN1, W_ih[r2 * 2 + 1] * s2};
  v2f bb  = {(b_ih[r1] + b_hh[r1]) * KN1, (b_ih[r2] + b_hh[r2]) * s2};

  // Rotation weights: at iteration m this lane sees h_{(j-m)&7}.
  v2f wrot[8];
  #pragma unroll
  for (int m = 0; m < 8; ++m) {
    const int k = (j - m) & 7;               // <-- direction fix vs R5
    wrot[m] = (k < H) ? (v2f){W_hh[r1 * H + k] * KN1, W_hh[r2 * H + k] * s2}
                      : (v2f){0.0f, 0.0f};
  }

  float hsel = 0.0f;   // lane l holds h_{l&7} (junk for (l&7)>=5, zero-weighted)
  float CS   = 0.0f;   // scaled cell state c*KN2, valid on u1
  float h    = 0.0f;   // valid on u1

  const float2* __restrict__ x2 = (const float2*)x;

  auto step = [&](float2 xv) {
    v2f a = bb;
    a = __builtin_elementwise_fma((v2f){xv.x, xv.x}, wx0, a);
    a = __builtin_elementwise_fma((v2f){xv.y, xv.y}, wx1, a);
    float r = hsel;
    #pragma unroll
    for (int m = 0; m < 8; ++m) {
      a = __builtin_elementwise_fma((v2f){r, r}, wrot[m], a);
      if (m < 7) r = ROR1(r);
    }
    const float e1  = fexp2(a.x);
    const float e2  = fexp2(a.y);
    const float v1  = frcp(1.0f + e1);        // i (u0) / f (u1)
    const float r2v = frcp(1.0f + e2);
    const float gK  = fmaf(r2v, eA, eB);      // g*KN2 (u0) / o (u1)
    const float p   = v1 * gK;                // i*g*KN2 on u0
    const float pr  = ROR8(p);                // -> u1
    CS = fmaf(v1, CS, pr);                    // f*CS + i*g*KN2 (valid u1)
    const float et = fexp2(CS);               // exp(-2c)
    const float rt = frcp(1.0f + et);         // sigmoid(2c)
    const float o2 = gK + gK;                 // 2o on u1
    h = fmaf(rt, o2, -gK);                    // o*(2rt-1) = o*tanh(c)
    const float hr = ROR8(h);                 // u0 <- u1's h
    hsel = u ? h : hr;                        // lane l: h_{l&7}
  };

  // Ping-pong register prefetch of x, 4 steps deep.
  constexpr int CH = 4;
  float2 buf0[CH], buf1[CH];
  #pragma unroll
  for (int t = 0; t < CH; ++t) buf0[t] = x2[(size_t)t * B + chain];

  for (int t0 = 0; t0 < S; t0 += 2 * CH) {
    #pragma unroll
    for (int t = 0; t < CH; ++t) buf1[t] = x2[(size_t)(t0 + CH + t) * B + chain];
    #pragma unroll
    for (int t = 0; t < CH; ++t) step(buf0[t]);
    if (t0 + 2 * CH < S) {
      #pragma unroll
      for (int t = 0; t < CH; ++t) buf0[t] = x2[(size_t)(t0 + 2 * CH + t) * B + chain];
    }
    #pragma unroll
    for (int t = 0; t < CH; ++t) step(buf1[t]);
  }

  // out[chain] = sum_j h_j * W_lin[j] + b_lin; h_j on u1 lanes (j<H).
  float pv = (u == 1 && j < H) ? h * W_lin[jm] : 0.0f;
  pv += SWZ(pv, 0x41F);    // xor 1
  pv += SWZ(pv, 0x81F);    // xor 2
  pv += SWZ(pv, 0x101F);   // xor 4
  if ((tid & 15) == 8) out[chain] = pv + b_lin[0];
}

extern "C" void kernel_launch(void* const* d_in, const int* in_sizes, int n_in,
                              void* d_out, int out_size, void* d_ws, size_t ws_size,
                              hipStream_t stream) {
  const float* x     = (const float*)d_in[0];
  const float* W_ih  = (const float*)d_in[1];
  const float* W_hh  = (const float*)d_in[2];
  const float* b_ih  = (const float*)d_in[3];
  const float* b_hh  = (const float*)d_in[4];
  const float* W_lin = (const float*)d_in[5];
  const float* b_lin = (const float*)d_in[6];
  float* out = (float*)d_out;

  const int threads = B * 16;          // 131072 -> 2048 waves -> 2/SIMD
  dim3 grid(threads / 256), block(256);
  hipLaunchKernelGGL(lstm_kernel, grid, block, 0, stream,
                     x, W_ih, W_hh, b_ih, b_hh, W_lin, b_lin, out);
}